// Round 1
// baseline (1264.027 us; speedup 1.0000x reference)
//
#include <hip/hip_runtime.h>
#include <stdint.h>

#define N_EDGES 2000000
#define NUM_SEG 500000
#define HID 128
#define NBLK 4

typedef __attribute__((ext_vector_type(8))) unsigned short ushort8;
typedef __attribute__((ext_vector_type(8))) __bf16 bf16x8;
typedef __attribute__((ext_vector_type(4))) float float4v;

__device__ inline unsigned short f32_to_bf16(float f) {
    union { float f; uint32_t u; } v; v.f = f;
    uint32_t u = v.u;
    u += 0x7fffu + ((u >> 16) & 1u);   // RNE
    return (unsigned short)(u >> 16);
}

// ---- prep: Wb[blk][j][k] = bf16(W_res[blk][j][k] * rms_w[blk][k])  (rms_w folded)
__global__ void prep_kernel(const float* __restrict__ W_res,
                            const float* __restrict__ rms_w,
                            unsigned short* __restrict__ Wb) {
    int i = blockIdx.x * 256 + threadIdx.x;
    if (i < NBLK * HID * HID) {
        int blk = i >> 14;
        int k = i & (HID - 1);
        Wb[i] = f32_to_bf16(W_res[i] * rms_w[blk * HID + k]);
    }
}

__global__ void fill_kernel(uint32_t* __restrict__ segmax, float* __restrict__ segsum) {
    int i = blockIdx.x * 256 + threadIdx.x;
    if (i < NUM_SEG) { segmax[i] = 0u; segsum[i] = 0.0f; }
}

// ---- fused MLP: 128 rows per workgroup, 4 waves x 32 rows, h in C-layout registers
__launch_bounds__(256, 2)
__global__ void mlp_kernel(const float* __restrict__ x,       // [N,3]
                           const float* __restrict__ W_in,    // [128,3]
                           const float* __restrict__ b_in,    // [128]
                           const unsigned short* __restrict__ Wb, // [4,128,128] bf16 (rms_w folded)
                           const float* __restrict__ b_res,   // [4,128]
                           const float* __restrict__ W_out,   // [128]
                           const float* __restrict__ b_out,   // [1]
                           float* __restrict__ logits) {      // [N]
    __shared__ unsigned short hn[128][136];  // bf16 A-staging, stride 136 (16B-aligned rows)
    __shared__ float xs[128 * 3];
    __shared__ float win_s[HID * 3];
    __shared__ float bin_s[HID];
    __shared__ float br_s[NBLK * HID];
    __shared__ float wo_s[HID];

    const int t = threadIdx.x;
    const int wave = t >> 6;
    const int lane = t & 63;
    const int q = lane >> 4;   // quad within wave
    const int c = lane & 15;   // lane within quad
    const long rowbase = (long)blockIdx.x * 128;

    for (int i = t; i < 384; i += 256) xs[i] = x[rowbase * 3 + i];
    for (int i = t; i < 384; i += 256) win_s[i] = W_in[i];
    if (t < HID) bin_s[t] = b_in[t];
    for (int i = t; i < NBLK * HID; i += 256) br_s[i] = b_res[i];
    if (t < HID) wo_s[t] = W_out[t];
    __syncthreads();

    // ---- stage 1: h0 = x @ W_in^T + b_in, directly into C-layout regs
    // C-layout (16x16x32): lane holds rows m = q*4+reg, col n = ct*16+c
    float4v h[2][8];
    {
        float xr[2][4][3];
        #pragma unroll
        for (int mt = 0; mt < 2; ++mt)
            #pragma unroll
            for (int reg = 0; reg < 4; ++reg) {
                int r = wave * 32 + mt * 16 + q * 4 + reg;
                #pragma unroll
                for (int k = 0; k < 3; ++k) xr[mt][reg][k] = xs[r * 3 + k];
            }
        #pragma unroll
        for (int ct = 0; ct < 8; ++ct) {
            int f = ct * 16 + c;
            float w0 = win_s[f * 3 + 0], w1 = win_s[f * 3 + 1], w2 = win_s[f * 3 + 2];
            float bb = bin_s[f];
            #pragma unroll
            for (int mt = 0; mt < 2; ++mt) {
                float4v v;
                #pragma unroll
                for (int reg = 0; reg < 4; ++reg)
                    v[reg] = bb + xr[mt][reg][0] * w0 + xr[mt][reg][1] * w1 + xr[mt][reg][2] * w2;
                h[mt][ct] = v;
            }
        }
    }

    // ---- residual blocks
    for (int blk = 0; blk < NBLK; ++blk) {
        // rmsnorm scale per row (reduce over 16 lanes of the quad via xor shuffles)
        float rs[2][4];
        #pragma unroll
        for (int mt = 0; mt < 2; ++mt)
            #pragma unroll
            for (int reg = 0; reg < 4; ++reg) {
                float ss = 0.0f;
                #pragma unroll
                for (int ct = 0; ct < 8; ++ct) { float vv = h[mt][ct][reg]; ss += vv * vv; }
                ss += __shfl_xor(ss, 1, 64);
                ss += __shfl_xor(ss, 2, 64);
                ss += __shfl_xor(ss, 4, 64);
                ss += __shfl_xor(ss, 8, 64);
                rs[mt][reg] = rsqrtf(ss * (1.0f / 128.0f) + 1.1920929e-7f);
            }
        // write normalized bf16 rows to LDS (rms_w already folded into Wb)
        #pragma unroll
        for (int mt = 0; mt < 2; ++mt)
            #pragma unroll
            for (int reg = 0; reg < 4; ++reg) {
                int r = wave * 32 + mt * 16 + q * 4 + reg;
                #pragma unroll
                for (int ct = 0; ct < 8; ++ct)
                    hn[r][ct * 16 + c] = f32_to_bf16(h[mt][ct][reg] * rs[mt][reg]);
            }
        // no barrier needed: each wave reads only its own 32 rows

        float4v acc[2][8];
        #pragma unroll
        for (int mt = 0; mt < 2; ++mt)
            #pragma unroll
            for (int ct = 0; ct < 8; ++ct) {
                float bb = br_s[blk * HID + ct * 16 + c];
                float4v av = {bb, bb, bb, bb};
                acc[mt][ct] = av;
            }
        const unsigned short* Wblk = Wb + blk * HID * HID;
        #pragma unroll
        for (int kt = 0; kt < 4; ++kt) {
            // A-frag: lane holds row m=c (within mtile), k = q*8+j (contiguous)
            bf16x8 a0 = __builtin_bit_cast(bf16x8,
                *(const ushort8*)&hn[wave * 32 + c][kt * 32 + q * 8]);
            bf16x8 a1 = __builtin_bit_cast(bf16x8,
                *(const ushort8*)&hn[wave * 32 + 16 + c][kt * 32 + q * 8]);
            #pragma unroll
            for (int ct = 0; ct < 8; ++ct) {
                // B-frag: lane holds n=c (W row = out-feature), k = q*8+j contiguous
                bf16x8 b = __builtin_bit_cast(bf16x8,
                    *(const ushort8*)&Wblk[(ct * 16 + c) * HID + kt * 32 + q * 8]);
                acc[0][ct] = __builtin_amdgcn_mfma_f32_16x16x32_bf16(a0, b, acc[0][ct], 0, 0, 0);
                acc[1][ct] = __builtin_amdgcn_mfma_f32_16x16x32_bf16(a1, b, acc[1][ct], 0, 0, 0);
            }
        }
        // relu + residual add
        #pragma unroll
        for (int mt = 0; mt < 2; ++mt)
            #pragma unroll
            for (int ct = 0; ct < 8; ++ct) {
                float4v y = acc[mt][ct];
                float4v hh = h[mt][ct];
                #pragma unroll
                for (int reg = 0; reg < 4; ++reg) hh[reg] = hh[reg] + fmaxf(y[reg], 0.0f);
                h[mt][ct] = hh;
            }
    }

    // ---- output head: logit = h . W_out + b_out
    float bo = b_out[0];
    float wov[8];
    #pragma unroll
    for (int ct = 0; ct < 8; ++ct) wov[ct] = wo_s[ct * 16 + c];
    #pragma unroll
    for (int mt = 0; mt < 2; ++mt)
        #pragma unroll
        for (int reg = 0; reg < 4; ++reg) {
            float s = 0.0f;
            #pragma unroll
            for (int ct = 0; ct < 8; ++ct) s += h[mt][ct][reg] * wov[ct];
            s += __shfl_xor(s, 1, 64);
            s += __shfl_xor(s, 2, 64);
            s += __shfl_xor(s, 4, 64);
            s += __shfl_xor(s, 8, 64);
            if (c == 0)
                logits[rowbase + wave * 32 + mt * 16 + q * 4 + reg] = s + bo;
        }
}

// ---- segment softmax over sorted ids (atomics; avg 4 rows/segment)
__device__ inline uint32_t enc_f(float f) {
    union { float f; uint32_t u; } v; v.f = f;
    return (v.u & 0x80000000u) ? ~v.u : (v.u | 0x80000000u);  // monotone float->uint
}
__device__ inline float dec_f(uint32_t u) {
    union { float f; uint32_t u; } v;
    v.u = (u & 0x80000000u) ? (u & 0x7fffffffu) : ~u;
    return v.f;
}

__global__ void segmax_kernel(const float* __restrict__ logits, const int* __restrict__ ids,
                              uint32_t* __restrict__ segmax) {
    int i = blockIdx.x * 256 + threadIdx.x;
    if (i < N_EDGES) atomicMax(&segmax[ids[i]], enc_f(logits[i]));
}

__global__ void segsum_kernel(const float* __restrict__ logits, const int* __restrict__ ids,
                              const uint32_t* __restrict__ segmax, float* __restrict__ segsum) {
    int i = blockIdx.x * 256 + threadIdx.x;
    if (i < N_EDGES) {
        int s = ids[i];
        atomicAdd(&segsum[s], expf(logits[i] - dec_f(segmax[s])));
    }
}

__global__ void norm_kernel(const float* __restrict__ logits, const int* __restrict__ ids,
                            const uint32_t* __restrict__ segmax, const float* __restrict__ segsum,
                            float* __restrict__ out) {
    int i = blockIdx.x * 256 + threadIdx.x;
    if (i < N_EDGES) {
        int s = ids[i];
        out[i] = expf(logits[i] - dec_f(segmax[s])) / segsum[s];
    }
}

extern "C" void kernel_launch(void* const* d_in, const int* in_sizes, int n_in,
                              void* d_out, int out_size, void* d_ws, size_t ws_size,
                              hipStream_t stream) {
    const float* x      = (const float*)d_in[0];
    const int*   ids    = (const int*)d_in[1];
    const float* W_in   = (const float*)d_in[2];
    const float* b_in   = (const float*)d_in[3];
    const float* rms_w  = (const float*)d_in[4];
    const float* W_res  = (const float*)d_in[5];
    const float* b_res  = (const float*)d_in[6];
    const float* W_out  = (const float*)d_in[7];
    const float* b_out  = (const float*)d_in[8];
    float* out = (float*)d_out;

    char* ws = (char*)d_ws;
    unsigned short* Wb = (unsigned short*)ws;                          // 131072 B
    float*    logits = (float*)(ws + 131072);                          // 8,000,000 B
    uint32_t* segmax = (uint32_t*)(ws + 131072 + 8000000);             // 2,000,000 B
    float*    segsum = (float*)(ws + 131072 + 8000000 + 2000000);      // 2,000,000 B

    prep_kernel<<<(NBLK * HID * HID + 255) / 256, 256, 0, stream>>>(W_res, rms_w, Wb);
    fill_kernel<<<(NUM_SEG + 255) / 256, 256, 0, stream>>>(segmax, segsum);
    mlp_kernel<<<N_EDGES / 128, 256, 0, stream>>>(x, W_in, b_in, Wb, b_res, W_out, b_out, logits);
    segmax_kernel<<<(N_EDGES + 255) / 256, 256, 0, stream>>>(logits, ids, segmax);
    segsum_kernel<<<(N_EDGES + 255) / 256, 256, 0, stream>>>(logits, ids, segmax, segsum);
    norm_kernel<<<(N_EDGES + 255) / 256, 256, 0, stream>>>(logits, ids, segmax, segsum, out);
}

// Round 2
// 791.599 us; speedup vs baseline: 1.5968x; 1.5968x over previous
//
#include <hip/hip_runtime.h>
#include <stdint.h>

#define N_EDGES 2000000
#define NUM_SEG 500000
#define HID 128
#define NBLK 4

typedef __attribute__((ext_vector_type(8))) unsigned short ushort8;
typedef __attribute__((ext_vector_type(8))) __bf16 bf16x8;
typedef __attribute__((ext_vector_type(4))) float float4v;

__device__ inline unsigned short f32_to_bf16(float f) {
    return __builtin_bit_cast(unsigned short, (__bf16)f);   // native cvt, RNE
}

// ---- prep: Wb[blk][j][k] = bf16(W_res[blk][j][k] * rms_w[blk][k])  (rms_w folded)
__global__ void prep_kernel(const float* __restrict__ W_res,
                            const float* __restrict__ rms_w,
                            unsigned short* __restrict__ Wb) {
    int i = blockIdx.x * 256 + threadIdx.x;
    if (i < NBLK * HID * HID) {
        int blk = i >> 14;
        int k = i & (HID - 1);
        Wb[i] = f32_to_bf16(W_res[i] * rms_w[blk * HID + k]);
    }
}

__global__ void fill_kernel(uint32_t* __restrict__ segmax, float* __restrict__ segsum) {
    int i = blockIdx.x * 256 + threadIdx.x;
    if (i < NUM_SEG) { segmax[i] = 0u; segsum[i] = 0.0f; }
}

// ---- fused MLP: 128 rows per workgroup, 4 waves x 32 rows, h in C-layout registers.
// W for the current residual block lives in LDS (staged per block, next block's W
// prefetched into registers during the MFMA loop).
__launch_bounds__(256, 2)
__global__ void mlp_kernel(const float* __restrict__ x,       // [N,3]
                           const float* __restrict__ W_in,    // [128,3]
                           const float* __restrict__ b_in,    // [128]
                           const unsigned short* __restrict__ Wb, // [4,128,128] bf16 (rms_w folded)
                           const float* __restrict__ b_res,   // [4,128]
                           const float* __restrict__ W_out,   // [128]
                           const float* __restrict__ b_out,   // [1]
                           float* __restrict__ logits) {      // [N]
    __shared__ unsigned short hn[128][136];  // bf16 A-staging, stride 136 (16B-aligned rows)
    __shared__ unsigned short Ws[128][136];  // current block's W (bf16, rms_w folded)
    __shared__ float xs[128 * 3];

    const int t = threadIdx.x;
    const int wave = t >> 6;
    const int lane = t & 63;
    const int q = lane >> 4;   // quad within wave
    const int c = lane & 15;   // lane within quad
    const long rowbase = (long)blockIdx.x * 128;

    // prefetch W for blk 0 into registers (8 x 16B per thread covers 32KB/wg)
    ushort8 wreg[8];
    #pragma unroll
    for (int i = 0; i < 8; ++i) {
        int ci = i * 256 + t;          // chunk id: f = ci>>4, g = ci&15
        wreg[i] = *(const ushort8*)&Wb[(ci >> 4) * HID + (ci & 15) * 8];
    }

    for (int i = t; i < 384; i += 256) xs[i] = x[rowbase * 3 + i];
    __syncthreads();

    // ---- stage 1: h0 = x @ W_in^T + b_in, directly into C-layout regs
    // C-layout (16x16x32): lane holds rows m = q*4+reg, col n = ct*16+c
    float4v h[2][8];
    {
        float xr[2][4][3];
        #pragma unroll
        for (int mt = 0; mt < 2; ++mt)
            #pragma unroll
            for (int reg = 0; reg < 4; ++reg) {
                int r = wave * 32 + mt * 16 + q * 4 + reg;
                #pragma unroll
                for (int k = 0; k < 3; ++k) xr[mt][reg][k] = xs[r * 3 + k];
            }
        #pragma unroll
        for (int ct = 0; ct < 8; ++ct) {
            int f = ct * 16 + c;
            float w0 = W_in[f * 3 + 0], w1 = W_in[f * 3 + 1], w2 = W_in[f * 3 + 2];
            float bb = b_in[f];
            #pragma unroll
            for (int mt = 0; mt < 2; ++mt) {
                float4v v;
                #pragma unroll
                for (int reg = 0; reg < 4; ++reg)
                    v[reg] = bb + xr[mt][reg][0] * w0 + xr[mt][reg][1] * w1 + xr[mt][reg][2] * w2;
                h[mt][ct] = v;
            }
        }
    }

    // ---- residual blocks
    for (int blk = 0; blk < NBLK; ++blk) {
        // publish this block's W to LDS
        #pragma unroll
        for (int i = 0; i < 8; ++i) {
            int ci = i * 256 + t;
            *(ushort8*)&Ws[ci >> 4][(ci & 15) * 8] = wreg[i];
        }
        __syncthreads();
        // prefetch next block's W (global loads in flight during MFMA)
        if (blk < NBLK - 1) {
            const unsigned short* Wn = Wb + (blk + 1) * HID * HID;
            #pragma unroll
            for (int i = 0; i < 8; ++i) {
                int ci = i * 256 + t;
                wreg[i] = *(const ushort8*)&Wn[(ci >> 4) * HID + (ci & 15) * 8];
            }
        }

        // rmsnorm scale per row (reduce over 16 lanes of the quad via xor shuffles)
        float rs[2][4];
        #pragma unroll
        for (int mt = 0; mt < 2; ++mt)
            #pragma unroll
            for (int reg = 0; reg < 4; ++reg) {
                float ss = 0.0f;
                #pragma unroll
                for (int ct = 0; ct < 8; ++ct) { float vv = h[mt][ct][reg]; ss += vv * vv; }
                ss += __shfl_xor(ss, 1, 64);
                ss += __shfl_xor(ss, 2, 64);
                ss += __shfl_xor(ss, 4, 64);
                ss += __shfl_xor(ss, 8, 64);
                rs[mt][reg] = rsqrtf(ss * (1.0f / 128.0f) + 1.1920929e-7f);
            }
        // write normalized bf16 rows to LDS (rms_w already folded into Wb)
        #pragma unroll
        for (int mt = 0; mt < 2; ++mt)
            #pragma unroll
            for (int reg = 0; reg < 4; ++reg) {
                int r = wave * 32 + mt * 16 + q * 4 + reg;
                #pragma unroll
                for (int ct = 0; ct < 8; ++ct)
                    hn[r][ct * 16 + c] = f32_to_bf16(h[mt][ct][reg] * rs[mt][reg]);
            }
        // no barrier needed for hn: each wave reads only its own 32 rows

        float4v acc[2][8];
        #pragma unroll
        for (int mt = 0; mt < 2; ++mt)
            #pragma unroll
            for (int ct = 0; ct < 8; ++ct) {
                float bb = b_res[blk * HID + ct * 16 + c];
                float4v av = {bb, bb, bb, bb};
                acc[mt][ct] = av;
            }
        #pragma unroll
        for (int kt = 0; kt < 4; ++kt) {
            // A-frag: lane holds row m=c (within mtile), k = q*8+j (contiguous)
            bf16x8 a0 = __builtin_bit_cast(bf16x8,
                *(const ushort8*)&hn[wave * 32 + c][kt * 32 + q * 8]);
            bf16x8 a1 = __builtin_bit_cast(bf16x8,
                *(const ushort8*)&hn[wave * 32 + 16 + c][kt * 32 + q * 8]);
            #pragma unroll
            for (int ct = 0; ct < 8; ++ct) {
                // B-frag from LDS: lane holds n=c (out-feature row), k = q*8+j contiguous
                bf16x8 b = __builtin_bit_cast(bf16x8,
                    *(const ushort8*)&Ws[ct * 16 + c][kt * 32 + q * 8]);
                acc[0][ct] = __builtin_amdgcn_mfma_f32_16x16x32_bf16(a0, b, acc[0][ct], 0, 0, 0);
                acc[1][ct] = __builtin_amdgcn_mfma_f32_16x16x32_bf16(a1, b, acc[1][ct], 0, 0, 0);
            }
        }
        // relu + residual add
        #pragma unroll
        for (int mt = 0; mt < 2; ++mt)
            #pragma unroll
            for (int ct = 0; ct < 8; ++ct) {
                float4v y = acc[mt][ct];
                float4v hh = h[mt][ct];
                #pragma unroll
                for (int reg = 0; reg < 4; ++reg) hh[reg] = hh[reg] + fmaxf(y[reg], 0.0f);
                h[mt][ct] = hh;
            }
        __syncthreads();   // all waves done reading Ws before next block overwrites
    }

    // ---- output head: logit = h . W_out + b_out
    float bo = b_out[0];
    float wov[8];
    #pragma unroll
    for (int ct = 0; ct < 8; ++ct) wov[ct] = W_out[ct * 16 + c];
    #pragma unroll
    for (int mt = 0; mt < 2; ++mt)
        #pragma unroll
        for (int reg = 0; reg < 4; ++reg) {
            float s = 0.0f;
            #pragma unroll
            for (int ct = 0; ct < 8; ++ct) s += h[mt][ct][reg] * wov[ct];
            s += __shfl_xor(s, 1, 64);
            s += __shfl_xor(s, 2, 64);
            s += __shfl_xor(s, 4, 64);
            s += __shfl_xor(s, 8, 64);
            if (c == 0)
                logits[rowbase + wave * 32 + mt * 16 + q * 4 + reg] = s + bo;
        }
}

// ---- segment softmax over sorted ids (atomics; avg 4 rows/segment)
__device__ inline uint32_t enc_f(float f) {
    union { float f; uint32_t u; } v; v.f = f;
    return (v.u & 0x80000000u) ? ~v.u : (v.u | 0x80000000u);  // monotone float->uint
}
__device__ inline float dec_f(uint32_t u) {
    union { float f; uint32_t u; } v;
    v.u = (u & 0x80000000u) ? (u & 0x7fffffffu) : ~u;
    return v.f;
}

__global__ void segmax_kernel(const float* __restrict__ logits, const int* __restrict__ ids,
                              uint32_t* __restrict__ segmax) {
    int i = blockIdx.x * 256 + threadIdx.x;
    if (i < N_EDGES) atomicMax(&segmax[ids[i]], enc_f(logits[i]));
}

__global__ void segsum_kernel(const float* __restrict__ logits, const int* __restrict__ ids,
                              const uint32_t* __restrict__ segmax, float* __restrict__ segsum) {
    int i = blockIdx.x * 256 + threadIdx.x;
    if (i < N_EDGES) {
        int s = ids[i];
        atomicAdd(&segsum[s], expf(logits[i] - dec_f(segmax[s])));
    }
}

__global__ void norm_kernel(const float* __restrict__ logits, const int* __restrict__ ids,
                            const uint32_t* __restrict__ segmax, const float* __restrict__ segsum,
                            float* __restrict__ out) {
    int i = blockIdx.x * 256 + threadIdx.x;
    if (i < N_EDGES) {
        int s = ids[i];
        out[i] = expf(logits[i] - dec_f(segmax[s])) / segsum[s];
    }
}

extern "C" void kernel_launch(void* const* d_in, const int* in_sizes, int n_in,
                              void* d_out, int out_size, void* d_ws, size_t ws_size,
                              hipStream_t stream) {
    const float* x      = (const float*)d_in[0];
    const int*   ids    = (const int*)d_in[1];
    const float* W_in   = (const float*)d_in[2];
    const float* b_in   = (const float*)d_in[3];
    const float* rms_w  = (const float*)d_in[4];
    const float* W_res  = (const float*)d_in[5];
    const float* b_res  = (const float*)d_in[6];
    const float* W_out  = (const float*)d_in[7];
    const float* b_out  = (const float*)d_in[8];
    float* out = (float*)d_out;

    char* ws = (char*)d_ws;
    unsigned short* Wb = (unsigned short*)ws;                          // 131072 B
    float*    logits = (float*)(ws + 131072);                          // 8,000,000 B
    uint32_t* segmax = (uint32_t*)(ws + 131072 + 8000000);             // 2,000,000 B
    float*    segsum = (float*)(ws + 131072 + 8000000 + 2000000);      // 2,000,000 B

    prep_kernel<<<(NBLK * HID * HID + 255) / 256, 256, 0, stream>>>(W_res, rms_w, Wb);
    fill_kernel<<<(NUM_SEG + 255) / 256, 256, 0, stream>>>(segmax, segsum);
    mlp_kernel<<<N_EDGES / 128, 256, 0, stream>>>(x, W_in, b_in, Wb, b_res, W_out, b_out, logits);
    segmax_kernel<<<(N_EDGES + 255) / 256, 256, 0, stream>>>(logits, ids, segmax);
    segsum_kernel<<<(N_EDGES + 255) / 256, 256, 0, stream>>>(logits, ids, segmax, segsum);
    norm_kernel<<<(N_EDGES + 255) / 256, 256, 0, stream>>>(logits, ids, segmax, segsum, out);
}

// Round 3
// 630.767 us; speedup vs baseline: 2.0040x; 1.2550x over previous
//
#include <hip/hip_runtime.h>
#include <stdint.h>

#define N_EDGES 2000000
#define NUM_SEG 500000
#define HID 128
#define NBLK 4

typedef __attribute__((ext_vector_type(8))) unsigned short ushort8;
typedef __attribute__((ext_vector_type(8))) __bf16 bf16x8;
typedef __attribute__((ext_vector_type(4))) float float4v;

__device__ inline unsigned short f32_to_bf16(float f) {
    return __builtin_bit_cast(unsigned short, (__bf16)f);   // native cvt, RNE
}

// ---- prep (fused with segsum zero-fill):
// WbF[blk] holds bf16(W_res[blk][j][k] * rms_w[blk][k]) in B-FRAGMENT ORDER:
//   flat r = kt*4096 + ct*512 + lane*8 + j  ->  W[row=ct*16+(lane&15)][k=kt*32+(lane>>4)*8+j]
__global__ void prep_kernel(const float* __restrict__ W_res,
                            const float* __restrict__ rms_w,
                            unsigned short* __restrict__ WbF,
                            float* __restrict__ segsum) {
    int i = blockIdx.x * 256 + threadIdx.x;
    if (i < NBLK * HID * HID) {
        int blk = i >> 14;
        int r = i & 16383;
        int j = r & 7, lane = (r >> 3) & 63, ct = (r >> 9) & 7, kt = r >> 12;
        int c = lane & 15, q = lane >> 4;
        int row = ct * 16 + c;
        int k = kt * 32 + q * 8 + j;
        WbF[i] = f32_to_bf16(W_res[blk * 16384 + row * HID + k] * rms_w[blk * HID + k]);
    }
    int f = i - NBLK * HID * HID;
    if (f >= 0 && f < NUM_SEG) segsum[f] = 0.0f;
}

// ---- fused MLP: 128 rows/wg, 4 waves x 32 rows, h resident in C-layout registers.
// W in LDS in fragment order (immediate-offset ds_read_b128, conflict-free);
// RMSNorm scale deferred to the epilogue (rs * acc + b), so hn writes need no rs.
__launch_bounds__(256, 2)
__global__ void mlp_kernel(const float* __restrict__ x,       // [N,3]
                           const float* __restrict__ W_in,    // [128,3]
                           const float* __restrict__ b_in,    // [128]
                           const unsigned short* __restrict__ WbF, // [4,16384] bf16 frag-order
                           const float* __restrict__ b_res,   // [4,128]
                           const float* __restrict__ W_out,   // [128]
                           const float* __restrict__ b_out,   // [1]
                           float* __restrict__ e) {           // [N] = exp(logit)
    __shared__ __align__(16) unsigned short WsF[16384];   // 32 KB, fragment order
    __shared__ __align__(16) unsigned short hn[128][136]; // bf16 A-staging, 17-group stride
    __shared__ float xs[128 * 3];

    const int t = threadIdx.x;
    const int wave = t >> 6;
    const int lane = t & 63;
    const int q = lane >> 4;   // quad within wave
    const int c = lane & 15;   // lane within quad
    const long rowbase = (long)blockIdx.x * 128;

    // prefetch W for blk 0 (linear: chunk ci = i*256+t)
    ushort8 wreg[8];
    #pragma unroll
    for (int i = 0; i < 8; ++i)
        wreg[i] = *(const ushort8*)&WbF[(i * 256 + t) * 8];

    for (int i = t; i < 384; i += 256) xs[i] = x[rowbase * 3 + i];
    __syncthreads();

    // ---- stage 1: h0 = x @ W_in^T + b_in, directly into C-layout regs
    // C-layout (16x16x32): lane holds rows m = q*4+reg, col n = ct*16+c
    float4v h[2][8];
    {
        float xr[2][4][3];
        #pragma unroll
        for (int mt = 0; mt < 2; ++mt)
            #pragma unroll
            for (int reg = 0; reg < 4; ++reg) {
                int r = wave * 32 + mt * 16 + q * 4 + reg;
                #pragma unroll
                for (int k = 0; k < 3; ++k) xr[mt][reg][k] = xs[r * 3 + k];
            }
        #pragma unroll
        for (int ct = 0; ct < 8; ++ct) {
            int f = ct * 16 + c;
            float w0 = W_in[f * 3 + 0], w1 = W_in[f * 3 + 1], w2 = W_in[f * 3 + 2];
            float bb = b_in[f];
            #pragma unroll
            for (int mt = 0; mt < 2; ++mt) {
                float4v v;
                #pragma unroll
                for (int reg = 0; reg < 4; ++reg)
                    v[reg] = bb + xr[mt][reg][0] * w0 + xr[mt][reg][1] * w1 + xr[mt][reg][2] * w2;
                h[mt][ct] = v;
            }
        }
    }

    // ---- residual blocks
    for (int blk = 0; blk < NBLK; ++blk) {
        // publish this block's W to LDS (lane-contiguous, conflict-free)
        #pragma unroll
        for (int i = 0; i < 8; ++i)
            *(ushort8*)&WsF[(i * 256 + t) * 8] = wreg[i];
        __syncthreads();
        // prefetch next block's W (in flight during MFMA)
        if (blk < NBLK - 1) {
            const unsigned short* Wn = WbF + (blk + 1) * 16384;
            #pragma unroll
            for (int i = 0; i < 8; ++i)
                wreg[i] = *(const ushort8*)&Wn[(i * 256 + t) * 8];
        }

        // write RAW h as bf16 to LDS immediately (rs deferred to epilogue)
        #pragma unroll
        for (int mt = 0; mt < 2; ++mt)
            #pragma unroll
            for (int reg = 0; reg < 4; ++reg) {
                int r = wave * 32 + mt * 16 + q * 4 + reg;
                #pragma unroll
                for (int ct = 0; ct < 8; ++ct)
                    hn[r][ct * 16 + c] = f32_to_bf16(h[mt][ct][reg]);
            }

        // rmsnorm scale per row (off the critical path now)
        float rs[2][4];
        #pragma unroll
        for (int mt = 0; mt < 2; ++mt)
            #pragma unroll
            for (int reg = 0; reg < 4; ++reg) {
                float ss = 0.0f;
                #pragma unroll
                for (int ct = 0; ct < 8; ++ct) { float vv = h[mt][ct][reg]; ss += vv * vv; }
                ss += __shfl_xor(ss, 1, 64);
                ss += __shfl_xor(ss, 2, 64);
                ss += __shfl_xor(ss, 4, 64);
                ss += __shfl_xor(ss, 8, 64);
                rs[mt][reg] = rsqrtf(ss * (1.0f / 128.0f) + 1.1920929e-7f);
            }

        float4v acc[2][8] = {};
        #pragma unroll
        for (int kt = 0; kt < 4; ++kt) {
            // A-frag: lane holds row m=c (within mtile), k = q*8+j contiguous
            bf16x8 a0 = __builtin_bit_cast(bf16x8,
                *(const ushort8*)&hn[wave * 32 + c][kt * 32 + q * 8]);
            bf16x8 a1 = __builtin_bit_cast(bf16x8,
                *(const ushort8*)&hn[wave * 32 + 16 + c][kt * 32 + q * 8]);
            #pragma unroll
            for (int ct = 0; ct < 8; ++ct) {
                // B-frag: fragment order -> base lane*16B + immediate offset
                bf16x8 b = __builtin_bit_cast(bf16x8,
                    *(const ushort8*)&WsF[((kt * 8 + ct) * 64 + lane) * 8]);
                acc[0][ct] = __builtin_amdgcn_mfma_f32_16x16x32_bf16(a0, b, acc[0][ct], 0, 0, 0);
                acc[1][ct] = __builtin_amdgcn_mfma_f32_16x16x32_bf16(a1, b, acc[1][ct], 0, 0, 0);
            }
        }
        // epilogue: h += relu(rs * acc + b_res)
        #pragma unroll
        for (int ct = 0; ct < 8; ++ct) {
            float bb = b_res[blk * HID + ct * 16 + c];
            #pragma unroll
            for (int mt = 0; mt < 2; ++mt) {
                float4v y = acc[mt][ct];
                float4v hh = h[mt][ct];
                #pragma unroll
                for (int reg = 0; reg < 4; ++reg)
                    hh[reg] = hh[reg] + fmaxf(fmaf(rs[mt][reg], y[reg], bb), 0.0f);
                h[mt][ct] = hh;
            }
        }
        __syncthreads();   // all waves done reading WsF before next publish
    }

    // ---- output head: e = exp(h . W_out + b_out)
    float bo = b_out[0];
    float wov[8];
    #pragma unroll
    for (int ct = 0; ct < 8; ++ct) wov[ct] = W_out[ct * 16 + c];
    #pragma unroll
    for (int mt = 0; mt < 2; ++mt)
        #pragma unroll
        for (int reg = 0; reg < 4; ++reg) {
            float s = 0.0f;
            #pragma unroll
            for (int ct = 0; ct < 8; ++ct) s += h[mt][ct][reg] * wov[ct];
            s += __shfl_xor(s, 1, 64);
            s += __shfl_xor(s, 2, 64);
            s += __shfl_xor(s, 4, 64);
            s += __shfl_xor(s, 8, 64);
            if (c == 0)
                e[rowbase + wave * 32 + mt * 16 + q * 4 + reg] = __expf(s + bo);
        }
}

// ---- segment sum of e (sorted ids): wave-level segmented scan, tail lanes atomicAdd
__global__ void segsum_kernel(const float* __restrict__ e, const int* __restrict__ ids,
                              float* __restrict__ segsum) {
    int i = blockIdx.x * 256 + threadIdx.x;
    int lane = threadIdx.x & 63;
    float v = 0.0f; int id = -1;
    if (i < N_EDGES) { v = e[i]; id = ids[i]; }
    #pragma unroll
    for (int d = 1; d < 64; d <<= 1) {
        float ov = __shfl_up(v, d, 64);
        int oid = __shfl_up(id, d, 64);
        if (lane >= d && oid == id) v += ov;
    }
    int nid = __shfl_down(id, 1, 64);
    bool tail = (lane == 63) || (nid != id);
    if (id >= 0 && tail) atomicAdd(&segsum[id], v);
}

__global__ void norm_kernel(const float* __restrict__ e, const int* __restrict__ ids,
                            const float* __restrict__ segsum, float* __restrict__ out) {
    int i = blockIdx.x * 256 + threadIdx.x;
    if (i < N_EDGES) out[i] = e[i] / segsum[ids[i]];
}

extern "C" void kernel_launch(void* const* d_in, const int* in_sizes, int n_in,
                              void* d_out, int out_size, void* d_ws, size_t ws_size,
                              hipStream_t stream) {
    const float* x      = (const float*)d_in[0];
    const int*   ids    = (const int*)d_in[1];
    const float* W_in   = (const float*)d_in[2];
    const float* b_in   = (const float*)d_in[3];
    const float* rms_w  = (const float*)d_in[4];
    const float* W_res  = (const float*)d_in[5];
    const float* b_res  = (const float*)d_in[6];
    const float* W_out  = (const float*)d_in[7];
    const float* b_out  = (const float*)d_in[8];
    float* out = (float*)d_out;

    char* ws = (char*)d_ws;
    unsigned short* WbF = (unsigned short*)ws;                 // 131072 B
    float* e      = (float*)(ws + 131072);                     // 8,000,000 B
    float* segsum = (float*)(ws + 131072 + 8000000);           // 2,000,000 B

    int prep_grid = (NBLK * HID * HID + NUM_SEG + 255) / 256;
    prep_kernel<<<prep_grid, 256, 0, stream>>>(W_res, rms_w, WbF, segsum);
    mlp_kernel<<<N_EDGES / 128, 256, 0, stream>>>(x, W_in, b_in, WbF, b_res, W_out, b_out, e);
    segsum_kernel<<<(N_EDGES + 255) / 256, 256, 0, stream>>>(e, ids, segsum);
    norm_kernel<<<(N_EDGES + 255) / 256, 256, 0, stream>>>(e, ids, segsum, out);
}

// Round 4
// 535.556 us; speedup vs baseline: 2.3602x; 1.1778x over previous
//
#include <hip/hip_runtime.h>
#include <stdint.h>

#define N_EDGES 2000000
#define NUM_SEG 500000
#define HID 128
#define NBLK 4

typedef __attribute__((ext_vector_type(8))) unsigned short ushort8;
typedef __attribute__((ext_vector_type(8))) __bf16 bf16x8;
typedef __attribute__((ext_vector_type(4))) float float4v;
typedef __attribute__((ext_vector_type(2))) uint32_t uint2v;

__device__ inline unsigned short f32_to_bf16(float f) {
    return __builtin_bit_cast(unsigned short, (__bf16)f);   // native cvt, RNE
}

__device__ inline uint32_t pack_bf16(float lo, float hi) {
#if __has_builtin(__builtin_amdgcn_cvt_pk_bf16_f32)
    typedef __attribute__((ext_vector_type(2))) __bf16 bf16x2;
    bf16x2 r = __builtin_amdgcn_cvt_pk_bf16_f32(lo, hi);
    return __builtin_bit_cast(uint32_t, r);
#else
    return (uint32_t)f32_to_bf16(lo) | ((uint32_t)f32_to_bf16(hi) << 16);
#endif
}

// ---- prep: WbF[blk] = bf16(W_res*rms_w) in A-FRAGMENT ORDER (same bytes as R3):
//   i = blk*16384 + (kt*8+ft)*512 + lane*8 + j -> W'[m=ft*16+(lane&15)][k=kt*32+(lane>>4)*8+j]
// Also packs Win4[f] = {W_in[f][0..2], b_in[f]} and zero-fills segsum.
__global__ void prep_kernel(const float* __restrict__ W_res,
                            const float* __restrict__ rms_w,
                            const float* __restrict__ W_in,
                            const float* __restrict__ b_in,
                            unsigned short* __restrict__ WbF,
                            float* __restrict__ Win4,
                            float* __restrict__ segsum) {
    int i = blockIdx.x * 256 + threadIdx.x;
    if (i < 65536) {
        int blk = i >> 14;
        int r = i & 16383;
        int j = r & 7, lane = (r >> 3) & 63, ft = (r >> 9) & 7, kt = r >> 12;
        int cc = lane & 15, qq = lane >> 4;
        int row = ft * 16 + cc;
        int k = kt * 32 + qq * 8 + j;
        WbF[i] = f32_to_bf16(W_res[blk * 16384 + row * HID + k] * rms_w[blk * HID + k]);
    } else if (i < 65536 + 128) {
        int f = i - 65536;
        Win4[f * 4 + 0] = W_in[f * 3 + 0];
        Win4[f * 4 + 1] = W_in[f * 3 + 1];
        Win4[f * 4 + 2] = W_in[f * 3 + 2];
        Win4[f * 4 + 3] = b_in[f];
    } else {
        int s = i - 65536 - 128;
        if (s < NUM_SEG) segsum[s] = 0.0f;
    }
}

// ---- fused MLP: 128 rows/wg, 4 waves x 32 rows.
// h resident in D[f][r] layout: lane (q,c) holds h[f=ft*16+q*4+reg][r=wave*32+rt*16+c].
// MFMA: y = W' (A) x hn^T (B). hn staged in B-frag order via packed-bf16 ds_write_b64.
__launch_bounds__(256, 2)
__global__ void mlp_kernel(const float* __restrict__ x,           // [N,3]
                           const unsigned short* __restrict__ WbF,// [4,16384] bf16 A-frag order
                           const float* __restrict__ b_res,       // [4,128]
                           const float* __restrict__ W_out,       // [128]
                           const float* __restrict__ b_out,       // [1]
                           const float* __restrict__ Win4g,       // [128,4] = {w0,w1,w2,b_in}
                           float* __restrict__ e) {               // [N] = exp(logit)
    __shared__ __align__(16) unsigned short WsF[16384];   // 32 KB, A-frag order
    __shared__ __align__(16) unsigned short hnF[16384];   // 32 KB, B-frag order (8KB/wave)
    __shared__ __align__(16) float4v Win4[128];
    __shared__ float xs[384];

    const int t = threadIdx.x;
    const int wave = t >> 6;
    const int lane = t & 63;
    const int q = lane >> 4;   // quad within wave
    const int c = lane & 15;   // lane within quad
    const long rowbase = (long)blockIdx.x * 128;

    // prefetch W for blk 0 (lane-linear)
    ushort8 wreg[8];
    #pragma unroll
    for (int i = 0; i < 8; ++i)
        wreg[i] = *(const ushort8*)&WbF[(i * 256 + t) * 8];

    for (int i = t; i < 384; i += 256) xs[i] = x[rowbase * 3 + i];
    if (t < 128) Win4[t] = ((const float4v*)Win4g)[t];
    __syncthreads();

    // ---- stage 1: h0[f][r] = W_in[f].x[r] + b_in[f], straight into D-layout regs
    float4v h[8][2];   // [ft][rt], component = reg
    {
        float xr[2][3];
        #pragma unroll
        for (int rt = 0; rt < 2; ++rt)
            #pragma unroll
            for (int k = 0; k < 3; ++k)
                xr[rt][k] = xs[(wave * 32 + rt * 16 + c) * 3 + k];
        #pragma unroll
        for (int ft = 0; ft < 8; ++ft)
            #pragma unroll
            for (int reg = 0; reg < 4; ++reg) {
                float4v wb = Win4[ft * 16 + q * 4 + reg];
                #pragma unroll
                for (int rt = 0; rt < 2; ++rt)
                    h[ft][rt][reg] = wb.w + xr[rt][0] * wb.x + xr[rt][1] * wb.y + xr[rt][2] * wb.z;
            }
    }

    // hnF write base (shorts): frag(rt, kt=ft>>1), lane_d = ((ft&1)*2+(q>>1))*16+c, j=(q&1)*4+reg
    const int wbase = wave * 4096 + (q >> 1) * 128 + c * 8 + (q & 1) * 4;
    const int rbase = wave * 4096 + lane * 8;   // B-frag read base (lane-linear)
    const float4v zero4 = {0.0f, 0.0f, 0.0f, 0.0f};

    // ---- residual blocks
    for (int blk = 0; blk < NBLK; ++blk) {
        // publish this block's W to LDS (lane-contiguous, conflict-free)
        #pragma unroll
        for (int i = 0; i < 8; ++i)
            *(ushort8*)&WsF[(i * 256 + t) * 8] = wreg[i];
        __syncthreads();
        // prefetch next block's W (in flight during MFMA)
        if (blk < NBLK - 1) {
            const unsigned short* Wn = WbF + (blk + 1) * 16384;
            #pragma unroll
            for (int i = 0; i < 8; ++i)
                wreg[i] = *(const ushort8*)&Wn[(i * 256 + t) * 8];
        }

        // write raw h as packed bf16 into B-frag-order LDS (16 x ds_write_b64)
        #pragma unroll
        for (int ft = 0; ft < 8; ++ft) {
            const int foff = (ft >> 1) * 1024 + (ft & 1) * 256;
            #pragma unroll
            for (int rt = 0; rt < 2; ++rt) {
                uint2v v;
                v.x = pack_bf16(h[ft][rt][0], h[ft][rt][1]);
                v.y = pack_bf16(h[ft][rt][2], h[ft][rt][3]);
                *(uint2v*)&hnF[wbase + foff + rt * 512] = v;
            }
        }

        // rmsnorm scale per row (row = rt*16+c; in-lane over ft,reg then xor over q)
        float rs[2];
        #pragma unroll
        for (int rt = 0; rt < 2; ++rt) {
            float ss = 0.0f;
            #pragma unroll
            for (int ft = 0; ft < 8; ++ft) {
                #pragma unroll
                for (int reg = 0; reg < 4; ++reg) {
                    float vv = h[ft][rt][reg];
                    ss += vv * vv;
                }
            }
            ss += __shfl_xor(ss, 16, 64);
            ss += __shfl_xor(ss, 32, 64);
            rs[rt] = rsqrtf(ss * (1.0f / 128.0f) + 1.1920929e-7f);
        }

        // MFMA: acc[ft][rt] = W'-frag(ft,kt) x hn-frag(rt,kt), kt=0 peeled (C=0)
        float4v acc[8][2];
        {
            bf16x8 b0 = __builtin_bit_cast(bf16x8, *(const ushort8*)&hnF[rbase + 0 * 512]);
            bf16x8 b1 = __builtin_bit_cast(bf16x8, *(const ushort8*)&hnF[rbase + 1 * 512]);
            #pragma unroll
            for (int ft = 0; ft < 8; ++ft) {
                bf16x8 a = __builtin_bit_cast(bf16x8, *(const ushort8*)&WsF[lane * 8 + ft * 512]);
                acc[ft][0] = __builtin_amdgcn_mfma_f32_16x16x32_bf16(a, b0, zero4, 0, 0, 0);
                acc[ft][1] = __builtin_amdgcn_mfma_f32_16x16x32_bf16(a, b1, zero4, 0, 0, 0);
            }
        }
        #pragma unroll
        for (int kt = 1; kt < 4; ++kt) {
            bf16x8 b0 = __builtin_bit_cast(bf16x8, *(const ushort8*)&hnF[rbase + (kt * 2 + 0) * 512]);
            bf16x8 b1 = __builtin_bit_cast(bf16x8, *(const ushort8*)&hnF[rbase + (kt * 2 + 1) * 512]);
            #pragma unroll
            for (int ft = 0; ft < 8; ++ft) {
                bf16x8 a = __builtin_bit_cast(bf16x8,
                    *(const ushort8*)&WsF[lane * 8 + (kt * 8 + ft) * 512]);
                acc[ft][0] = __builtin_amdgcn_mfma_f32_16x16x32_bf16(a, b0, acc[ft][0], 0, 0, 0);
                acc[ft][1] = __builtin_amdgcn_mfma_f32_16x16x32_bf16(a, b1, acc[ft][1], 0, 0, 0);
            }
        }

        // epilogue: h += relu(rs[rt]*acc + b_res[f])
        const float4v* br4 = (const float4v*)(b_res + blk * HID);
        #pragma unroll
        for (int ft = 0; ft < 8; ++ft) {
            float4v bb = br4[ft * 4 + q];
            #pragma unroll
            for (int rt = 0; rt < 2; ++rt) {
                #pragma unroll
                for (int reg = 0; reg < 4; ++reg)
                    h[ft][rt][reg] += fmaxf(fmaf(rs[rt], acc[ft][rt][reg], bb[reg]), 0.0f);
            }
        }
        __syncthreads();   // all waves done reading WsF before next publish
    }

    // ---- output head: e[r] = exp(h[.][r] . W_out + b_out)
    const float bo = b_out[0];
    const float4v* wo4 = (const float4v*)W_out;
    float s[2] = {0.0f, 0.0f};
    #pragma unroll
    for (int ft = 0; ft < 8; ++ft) {
        float4v w = wo4[ft * 4 + q];
        #pragma unroll
        for (int rt = 0; rt < 2; ++rt) {
            #pragma unroll
            for (int reg = 0; reg < 4; ++reg)
                s[rt] += h[ft][rt][reg] * w[reg];
        }
    }
    #pragma unroll
    for (int rt = 0; rt < 2; ++rt) {
        s[rt] += __shfl_xor(s[rt], 16, 64);
        s[rt] += __shfl_xor(s[rt], 32, 64);
    }
    if (q == 0) {
        #pragma unroll
        for (int rt = 0; rt < 2; ++rt)
            e[rowbase + wave * 32 + rt * 16 + c] = __expf(s[rt] + bo);
    }
}

// ---- segment sum of e (sorted ids): wave-level segmented scan, tail lanes atomicAdd
__global__ void segsum_kernel(const float* __restrict__ e, const int* __restrict__ ids,
                              float* __restrict__ segsum) {
    int i = blockIdx.x * 256 + threadIdx.x;
    int lane = threadIdx.x & 63;
    float v = 0.0f; int id = -1;
    if (i < N_EDGES) { v = e[i]; id = ids[i]; }
    #pragma unroll
    for (int d = 1; d < 64; d <<= 1) {
        float ov = __shfl_up(v, d, 64);
        int oid = __shfl_up(id, d, 64);
        if (lane >= d && oid == id) v += ov;
    }
    int nid = __shfl_down(id, 1, 64);
    bool tail = (lane == 63) || (nid != id);
    if (id >= 0 && tail) atomicAdd(&segsum[id], v);
}

__global__ void norm_kernel(const float* __restrict__ e, const int* __restrict__ ids,
                            const float* __restrict__ segsum, float* __restrict__ out) {
    int i = blockIdx.x * 256 + threadIdx.x;
    if (i < N_EDGES) out[i] = e[i] / segsum[ids[i]];
}

extern "C" void kernel_launch(void* const* d_in, const int* in_sizes, int n_in,
                              void* d_out, int out_size, void* d_ws, size_t ws_size,
                              hipStream_t stream) {
    const float* x      = (const float*)d_in[0];
    const int*   ids    = (const int*)d_in[1];
    const float* W_in   = (const float*)d_in[2];
    const float* b_in   = (const float*)d_in[3];
    const float* rms_w  = (const float*)d_in[4];
    const float* W_res  = (const float*)d_in[5];
    const float* b_res  = (const float*)d_in[6];
    const float* W_out  = (const float*)d_in[7];
    const float* b_out  = (const float*)d_in[8];
    float* out = (float*)d_out;

    char* ws = (char*)d_ws;
    unsigned short* WbF = (unsigned short*)ws;                 // 131072 B
    float* Win4   = (float*)(ws + 131072);                     // 2048 B
    float* e      = (float*)(ws + 131072 + 2048);              // 8,000,000 B
    float* segsum = (float*)(ws + 131072 + 2048 + 8000000);    // 2,000,000 B

    int prep_items = 65536 + 128 + NUM_SEG;
    prep_kernel<<<(prep_items + 255) / 256, 256, 0, stream>>>(W_res, rms_w, W_in, b_in,
                                                              WbF, Win4, segsum);
    mlp_kernel<<<N_EDGES / 128, 256, 0, stream>>>(x, WbF, b_res, W_out, b_out, Win4, e);
    segsum_kernel<<<(N_EDGES + 255) / 256, 256, 0, stream>>>(e, ids, segsum);
    norm_kernel<<<(N_EDGES + 255) / 256, 256, 0, stream>>>(e, ids, segsum, out);
}